// Round 4
// 419.654 us; speedup vs baseline: 1.1679x; 1.1679x over previous
//
#include <hip/hip_runtime.h>
#include <math.h>

typedef __attribute__((ext_vector_type(4)))  int   i32x4;
typedef __attribute__((ext_vector_type(16))) int   i32x16;
typedef __attribute__((ext_vector_type(4)))  float f32x4;

namespace {
constexpr int IN_F   = 4096;
constexpr int OUT_F  = 4096;
constexpr int TOKENS = 8192;
constexpr int PACKED = IN_F / 16;      // 256 words per weight row

constexpr int BM   = 256;
constexpr int BN   = 128;
constexpr int BK   = 128;              // i8 k per tile; 8 chunks of 16
constexpr int NTHR = 256;              // 4 waves, 2(M) x 2(N), wave tile 128x64
constexpr int NT   = IN_F / BK;        // 32 K-tiles

constexpr size_t XQ_BYTES = (size_t)TOKENS * IN_F;        // 33.55 MB
constexpr size_t XS_BYTES = (size_t)TOKENS * 4;           // 32 KB
constexpr size_t BQ_OFF   = XQ_BYTES + XS_BYTES;
constexpr size_t BQ_BYTES = (size_t)PACKED * OUT_F * 16;  // 16.78 MB
constexpr size_t WS_NEED  = BQ_OFF + BQ_BYTES;            // ~50.4 MB
}

// 16x 2-bit {0,1,2}  ->  16x i8 {-1,0,1}  (4 dwords)
__device__ __forceinline__ i32x4 unpack16(unsigned w) {
  i32x4 r;
#pragma unroll
  for (int g = 0; g < 4; ++g) {
    unsigned t = (w >> (8 * g)) & 0xFFu;
    unsigned s = (t | (t << 6) | (t << 12) | (t << 18)) & 0x03030303u;
    r[g] = (int)((((s | 0x80808080u) - 0x01010101u) ^ 0x80808080u));
  }
  return r;
}

// ---------------- pass 1a: per-row absmax + i8 quantize ----------------
__global__ __launch_bounds__(256)
void rowquant(const float* __restrict__ X, signed char* __restrict__ XQ,
              float* __restrict__ XS) {
  __shared__ float smax[4];
  const int row = blockIdx.x;
  const int t   = threadIdx.x;
  const float* xr = X + (size_t)row * IN_F + t * 16;

  f32x4 v[4];
  float m = 0.f;
#pragma unroll
  for (int j = 0; j < 4; ++j) {
    v[j] = *(const f32x4*)(xr + j * 4);
    m = fmaxf(m, fmaxf(fmaxf(fabsf(v[j].x), fabsf(v[j].y)),
                       fmaxf(fabsf(v[j].z), fabsf(v[j].w))));
  }
#pragma unroll
  for (int off = 32; off; off >>= 1) m = fmaxf(m, __shfl_xor(m, off, 64));
  if ((t & 63) == 0) smax[t >> 6] = m;
  __syncthreads();
  m = fmaxf(fmaxf(smax[0], smax[1]), fmaxf(smax[2], smax[3]));
  m = fmaxf(m, 1e-5f);
  const float r = 127.f / m;

  i32x4 d;
#pragma unroll
  for (int j = 0; j < 4; ++j) {
    int q0 = (int)rintf(v[j].x * r);
    int q1 = (int)rintf(v[j].y * r);
    int q2 = (int)rintf(v[j].z * r);
    int q3 = (int)rintf(v[j].w * r);
    d[j] = (q0 & 255) | ((q1 & 255) << 8) | ((q2 & 255) << 16) | ((q3 & 255) << 24);
  }
  *(i32x4*)(XQ + (size_t)row * IN_F + t * 16) = d;
  if (t == 0) XS[row] = m;
}

// ---------------- pass 1b: unpack ternary B once -> i8, chunk-major ----
__global__ __launch_bounds__(256)
void unpackB(const unsigned* __restrict__ PW, signed char* __restrict__ BQ) {
  const int g = blockIdx.x * 256 + threadIdx.x;   // 1M words
  const int c = g >> 12;                           // 0..255
  const int n = g & 4095;
  i32x4 u = unpack16(PW[(size_t)n * PACKED + c]);
  *(i32x4*)(BQ + ((size_t)c * OUT_F + n) * 16) = u;
}

// ---------------- pass 2 (fast): i8 GEMM, prefetch pipeline ------------
#define STAGE_A(BUF, KT)                                                        \
  {                                                                             \
    _Pragma("unroll")                                                           \
    for (int cc = 0; cc < 2; ++cc) {                                            \
      const int c_ = w * 2 + cc;                                                \
      _Pragma("unroll")                                                         \
      for (int rb = 0; rb < 4; ++rb) {                                          \
        const signed char* src =                                                \
            XQ + (size_t)(m0 + rb * 64 + lane) * IN_F + (KT) * BK + c_ * 16;    \
        signed char* dst = lA + (BUF) * 32768 + c_ * 4096 + rb * 1024;          \
        __builtin_amdgcn_global_load_lds(                                       \
            (const __attribute__((address_space(1))) void*)src,                 \
            (__attribute__((address_space(3))) void*)dst, 16, 0, 0);            \
      }                                                                         \
    }                                                                           \
  }

#define LOAD_B(B, KT)                                                           \
  {                                                                             \
    _Pragma("unroll")                                                           \
    for (int nf = 0; nf < 2; ++nf) {                                            \
      _Pragma("unroll")                                                         \
      for (int ks = 0; ks < 4; ++ks)                                            \
        B[nf][ks] = *(const i32x4*)(BQ +                                        \
            ((size_t)((KT) * 8 + ks * 2 + h) * OUT_F + nrow[nf]) * 16);         \
      }                                                                         \
  }

#define COMPUTE_TILE(BUFOFF, B)                                                 \
  {                                                                             \
    _Pragma("unroll")                                                           \
    for (int ks = 0; ks < 4; ++ks) {                                            \
      i32x4 afr[4];                                                             \
      _Pragma("unroll")                                                         \
      for (int mf = 0; mf < 4; ++mf)                                            \
        afr[mf] = *(const i32x4*)(lA + (BUFOFF) + (ks * 2 + h) * 4096 +         \
                                  (wm * 128 + mf * 32 + l31) * 16);             \
      _Pragma("unroll")                                                         \
      for (int mf = 0; mf < 4; ++mf) {                                          \
        acc[mf][0] = __builtin_amdgcn_mfma_i32_32x32x32_i8(afr[mf], B[0][ks],   \
                                                           acc[mf][0], 0, 0, 0);\
        acc[mf][1] = __builtin_amdgcn_mfma_i32_32x32x32_i8(afr[mf], B[1][ks],   \
                                                           acc[mf][1], 0, 0, 0);\
      }                                                                         \
    }                                                                           \
  }

__global__ __launch_bounds__(NTHR, 2)
void gemm_i8(const signed char* __restrict__ XQ, const signed char* __restrict__ BQ,
             const float* __restrict__ XS, const float* __restrict__ SC,
             float* __restrict__ OUT) {
  __shared__ signed char lA[2 * 32768];

  const int tid  = threadIdx.x;
  const int lane = tid & 63;
  const int w    = tid >> 6;     // 0..3
  const int wm   = w >> 1;       // 0..1
  const int wn   = w & 1;        // 0..1
  const int l31  = lane & 31;
  const int h    = lane >> 5;    // half-wave

  // bijective XCD swizzle: each XCD owns 4 contiguous n-block columns
  const int orig = blockIdx.y * gridDim.x + blockIdx.x;
  const int xcd  = orig & 7;
  const int idx  = orig >> 3;                  // 0..127
  const int m0   = (idx >> 2) * BM;
  const int n0   = (xcd * 4 + (idx & 3)) * BN;

  const int nrow[2] = { n0 + wn * 64 + 0 * 32 + l31,
                        n0 + wn * 64 + 1 * 32 + l31 };

  i32x16 acc[4][2];
#pragma unroll
  for (int mf = 0; mf < 4; ++mf)
#pragma unroll
    for (int nf = 0; nf < 2; ++nf)
      acc[mf][nf] = (i32x16)(0);

  i32x4 Ba[2][4], Bb[2][4];

  STAGE_A(0, 0);
  LOAD_B(Ba, 0);

  for (int kt = 0; kt < NT; kt += 2) {
    STAGE_A(1, kt + 1);
    LOAD_B(Bb, kt + 1);
    asm volatile("s_waitcnt vmcnt(16)" ::: "memory");  // tile kt resident
    __builtin_amdgcn_s_barrier();
    COMPUTE_TILE(0, Ba);
    asm volatile("" ::: "memory");
    __builtin_amdgcn_s_barrier();                      // buf0 free

    if (kt + 2 < NT) {
      STAGE_A(0, kt + 2);
      LOAD_B(Ba, kt + 2);
      asm volatile("s_waitcnt vmcnt(16)" ::: "memory");
    } else {
      asm volatile("s_waitcnt vmcnt(0)" ::: "memory");
    }
    __builtin_amdgcn_s_barrier();
    COMPUTE_TILE(32768, Bb);
    asm volatile("" ::: "memory");
    __builtin_amdgcn_s_barrier();
  }

  const float sc = SC[0] / 127.f;
#pragma unroll
  for (int mf = 0; mf < 4; ++mf) {
    float fs[16];
#pragma unroll
    for (int r = 0; r < 16; ++r) {
      const int mm = m0 + wm * 128 + mf * 32 + 4 * h + (r & 3) + 8 * (r >> 2);
      fs[r] = sc * XS[mm];
    }
#pragma unroll
    for (int nf = 0; nf < 2; ++nf) {
      const int ncol = n0 + wn * 64 + nf * 32 + l31;
#pragma unroll
      for (int r = 0; r < 16; ++r) {
        const int mm = m0 + wm * 128 + mf * 32 + 4 * h + (r & 3) + 8 * (r >> 2);
        OUT[(size_t)mm * OUT_F + ncol] = (float)acc[mf][nf][r] * fs[r];
      }
    }
  }
}

// ------- pass 2 (fallback, ws-small): verified Round-0 gemm, inline B -------
__global__ __launch_bounds__(NTHR, 2)
void gemm_i8_pw(const signed char* __restrict__ XQ, const unsigned* __restrict__ PW,
                const float* __restrict__ XS, const float* __restrict__ SC,
                float* __restrict__ OUT) {
  __shared__ signed char lA[BM * BK];

  const int tid  = threadIdx.x;
  const int lane = tid & 63;
  const int w    = tid >> 6;
  const int wm   = w >> 1;
  const int wn   = w & 1;
  const int l31  = lane & 31;
  const int h    = lane >> 5;

  const int m0 = blockIdx.y * BM;
  const int n0 = blockIdx.x * BN;

  i32x16 acc[4][2];
#pragma unroll
  for (int mf = 0; mf < 4; ++mf)
#pragma unroll
    for (int nf = 0; nf < 2; ++nf)
      acc[mf][nf] = (i32x16)(0);

  const unsigned* pb0 = PW + (size_t)(n0 + wn * 64 + 0 * 32 + l31) * PACKED;
  const unsigned* pb1 = PW + (size_t)(n0 + wn * 64 + 1 * 32 + l31) * PACKED;

  for (int kt = 0; kt < IN_F / BK; ++kt) {
#pragma unroll
    for (int cc = 0; cc < 2; ++cc) {
      const int c = w * 2 + cc;
#pragma unroll
      for (int rb = 0; rb < 4; ++rb) {
        const signed char* src =
            XQ + (size_t)(m0 + rb * 64 + lane) * IN_F + kt * BK + c * 16;
        signed char* dst = lA + c * 4096 + rb * 1024;
        __builtin_amdgcn_global_load_lds(
            (const __attribute__((address_space(1))) void*)src,
            (__attribute__((address_space(3))) void*)dst, 16, 0, 0);
      }
    }

    unsigned bw0[4], bw1[4];
#pragma unroll
    for (int ks = 0; ks < 4; ++ks) {
      bw0[ks] = pb0[kt * 8 + ks * 2 + h];
      bw1[ks] = pb1[kt * 8 + ks * 2 + h];
    }

    __syncthreads();

#pragma unroll
    for (int ks = 0; ks < 4; ++ks) {
      i32x4 bfr0 = unpack16(bw0[ks]);
      i32x4 bfr1 = unpack16(bw1[ks]);
      i32x4 afr[4];
#pragma unroll
      for (int mf = 0; mf < 4; ++mf)
        afr[mf] = *(const i32x4*)(lA + (ks * 2 + h) * 4096 +
                                  (wm * 128 + mf * 32 + l31) * 16);
#pragma unroll
      for (int mf = 0; mf < 4; ++mf) {
        acc[mf][0] = __builtin_amdgcn_mfma_i32_32x32x32_i8(afr[mf], bfr0, acc[mf][0], 0, 0, 0);
        acc[mf][1] = __builtin_amdgcn_mfma_i32_32x32x32_i8(afr[mf], bfr1, acc[mf][1], 0, 0, 0);
      }
    }
    __syncthreads();
  }

  const float sc = SC[0] / 127.f;
#pragma unroll
  for (int mf = 0; mf < 4; ++mf) {
    float fs[16];
#pragma unroll
    for (int r = 0; r < 16; ++r) {
      const int mm = m0 + wm * 128 + mf * 32 + 4 * h + (r & 3) + 8 * (r >> 2);
      fs[r] = sc * XS[mm];
    }
#pragma unroll
    for (int nf = 0; nf < 2; ++nf) {
      const int ncol = n0 + wn * 64 + nf * 32 + l31;
#pragma unroll
      for (int r = 0; r < 16; ++r) {
        const int mm = m0 + wm * 128 + mf * 32 + 4 * h + (r & 3) + 8 * (r >> 2);
        OUT[(size_t)mm * OUT_F + ncol] = (float)acc[mf][nf][r] * fs[r];
      }
    }
  }
}

extern "C" void kernel_launch(void* const* d_in, const int* in_sizes, int n_in,
                              void* d_out, int out_size, void* d_ws, size_t ws_size,
                              hipStream_t stream) {
  const float*    x  = (const float*)d_in[0];
  const unsigned* pw = (const unsigned*)d_in[1];
  const float*    sc = (const float*)d_in[2];
  float*          out = (float*)d_out;

  signed char* xq = (signed char*)d_ws;
  float*       xs = (float*)((char*)d_ws + XQ_BYTES);

  rowquant<<<dim3(TOKENS), dim3(256), 0, stream>>>(x, xq, xs);

  dim3 grid(OUT_F / BN, TOKENS / BM);  // (32, 32)
  if (ws_size >= WS_NEED) {
    // fast path: pre-unpacked B + pipelined gemm
    signed char* bq = (signed char*)d_ws + BQ_OFF;
    unpackB<<<dim3(OUT_F * PACKED / 256), dim3(256), 0, stream>>>(pw, bq);
    gemm_i8<<<grid, dim3(NTHR), 0, stream>>>(xq, bq, xs, sc, out);
  } else {
    // fallback: verified baseline gemm, inline ternary unpack (fits 33.6 MB ws)
    gemm_i8_pw<<<grid, dim3(NTHR), 0, stream>>>(xq, pw, xs, sc, out);
  }
}